// Round 11
// baseline (133.711 us; speedup 1.0000x reference)
//
#include <hip/hip_runtime.h>
#include <stdint.h>

typedef __bf16 bf16;
typedef __bf16 bf16x8 __attribute__((ext_vector_type(8)));
typedef float f32x4 __attribute__((ext_vector_type(4)));
typedef float f32x16 __attribute__((ext_vector_type(16)));

typedef __attribute__((address_space(1))) void gvoid_t;
typedef __attribute__((address_space(3))) void lvoid_t;

__device__ __forceinline__ void gload16(const void* src, void* lds) {
    __builtin_amdgcn_global_load_lds((gvoid_t*)src, (lvoid_t*)lds, 16, 0, 0);
}

// bare v_exp_f32: args bounded (|x| << 126), OCML range guard is dead weight
__device__ __forceinline__ float fexp2(float x) {
    float r;
    asm("v_exp_f32 %0, %1" : "=v"(r) : "v"(x));
    return r;
}

// ---------------- fused f32 -> bf16 convert (x, wqkv, wproj in one launch) ----------------
__global__ __launch_bounds__(256) void cvt3_kernel(const float* __restrict__ x,
                                                   const float* __restrict__ wqkv,
                                                   const float* __restrict__ wproj,
                                                   bf16* __restrict__ xb,
                                                   bf16* __restrict__ wqkvb,
                                                   bf16* __restrict__ wprojb) {
    int idx = blockIdx.x * 256 + threadIdx.x;
    int stride = gridDim.x * 256;
    for (int i = idx; i < 1048576; i += stride) {
        const float* in;
        bf16* out;
        int j;
        if (i < 524288) { in = x; out = xb; j = i; }
        else if (i < 917504) { in = wqkv; out = wqkvb; j = i - 524288; }
        else { in = wproj; out = wprojb; j = i - 917504; }
        const float4* p = (const float4*)in;
        float4 a = p[(long)j * 2], b = p[(long)j * 2 + 1];
        bf16x8 o;
        o[0] = (bf16)a.x; o[1] = (bf16)a.y; o[2] = (bf16)a.z; o[3] = (bf16)a.w;
        o[4] = (bf16)b.x; o[5] = (bf16)b.y; o[6] = (bf16)b.z; o[7] = (bf16)b.w;
        ((bf16x8*)out)[j] = o;
    }
}

// ------- GEMM: C[M,N] = A[M,K] * W[N,K]^T — 3-buffer counted-vmcnt pipeline -------
// NOTE: K-loop is hardcoded for K == 1024 (32 k-steps = 10*3 + 2). All call sites use K=1024.
template <bool F32OUT, int BN>
__global__ __launch_bounds__(256) void gemm_bt(const bf16* __restrict__ A,
                                               const bf16* __restrict__ W,
                                               const float* __restrict__ bias,
                                               void* __restrict__ Cout,
                                               const int M, const int N, const int K) {
    constexpr int NT = BN / 32;            // per-wave n-subtiles
    constexpr int BELEMS = BN * 32;
    __shared__ __align__(16) bf16 Alds[3 * 4096];    // 3 x [128][32]
    __shared__ __align__(16) bf16 Blds[3 * BELEMS];  // 3 x [BN][32]
    const int t = threadIdx.x;
    const int wid = t >> 6, lane = t & 63;
    const int g = lane >> 4, c = lane & 15;
    const int wm = wid >> 1, wn = wid & 1;
    const long bm = (long)blockIdx.y * 128, bn = (long)blockIdx.x * BN;

    f32x4 acc[4][NT] = {};

    const int arow = t >> 2;          // 0..63
    const int acol = (t & 3) * 8;     // elem offset
    const bf16* Asrc = A + (bm + arow) * (long)K + acol;
    const bf16* Bsrc = W + (bn + arow) * (long)K + acol;
    const int dstb = wid * 512;

#define GSTAGE(BI)                                                       \
    {                                                                    \
        bf16* ad = Alds + (BI) * 4096 + dstb;                            \
        bf16* bd = Blds + (BI) * BELEMS + dstb;                          \
        gload16(Asrc, ad);                                               \
        gload16(Asrc + (long)64 * K, ad + 2048);                         \
        gload16(Bsrc, bd);                                               \
        if constexpr (BN == 128) gload16(Bsrc + (long)64 * K, bd + 2048);\
        Asrc += 32;                                                      \
        Bsrc += 32;                                                      \
    }

    auto computeg = [&](int bi) __attribute__((always_inline)) {
        const bf16* Ab = Alds + bi * 4096;
        const bf16* Bb = Blds + bi * BELEMS;
        bf16x8 af[4], bfr[NT];
#pragma unroll
        for (int mt = 0; mt < 4; ++mt)
            af[mt] = *(const bf16x8*)(Ab + (wm * 64 + mt * 16 + c) * 32 + g * 8);
#pragma unroll
        for (int nt = 0; nt < NT; ++nt)
            bfr[nt] = *(const bf16x8*)(Bb + (wn * (BN / 2) + nt * 16 + c) * 32 + g * 8);
#pragma unroll
        for (int mt = 0; mt < 4; ++mt)
#pragma unroll
            for (int nt = 0; nt < NT; ++nt)
                acc[mt][nt] = __builtin_amdgcn_mfma_f32_16x16x32_bf16(af[mt], bfr[nt],
                                                                      acc[mt][nt], 0, 0, 0);
    };

    // steady-state wait: own tile's loads retired (FIFO), next tile's stay in flight
#define GWAITN                                                              \
    if constexpr (BN == 128) { asm volatile("s_waitcnt vmcnt(4)" ::: "memory"); } \
    else { asm volatile("s_waitcnt vmcnt(3)" ::: "memory"); }

#define GSTEP(CUR, NXT)            \
    GWAITN;                        \
    __builtin_amdgcn_s_barrier();  \
    GSTAGE(NXT);                   \
    computeg(CUR);

    GSTAGE(0);
    GSTAGE(1);
    for (int t3 = 0; t3 < 10; ++t3) {
        GSTEP(0, 2)
        GSTEP(1, 0)
        GSTEP(2, 1)
    }
    GWAITN;
    __builtin_amdgcn_s_barrier();
    computeg(0);
    asm volatile("s_waitcnt vmcnt(0)" ::: "memory");
    __builtin_amdgcn_s_barrier();
    computeg(1);
#undef GSTEP
#undef GWAITN
#undef GSTAGE

#pragma unroll
    for (int mt = 0; mt < 4; ++mt) {
#pragma unroll
        for (int nt = 0; nt < NT; ++nt) {
#pragma unroll
            for (int i = 0; i < 4; ++i) {
                const long row = bm + wm * 64 + mt * 16 + g * 4 + i;
                const long col = bn + wn * (BN / 2) + nt * 16 + c;
                if constexpr (F32OUT) {
                    ((float*)Cout)[row * N + col] = acc[mt][nt][i] + bias[col];
                } else {
                    ((bf16*)Cout)[row * N + col] = (bf16)acc[mt][nt][i];
                }
            }
        }
    }
}

// ---- Flash attention: 2 waves x 64 q (2 groups), K/V frags reg-reused across groups ----
// qk:  [4096 rows][2048] bf16 (Q cols 0-1023, K cols 1024-2047), row = b*2048+s
// Vt:  [1024 hd][4096] bf16 (V^T; col = b*2048 + s)
// LDS: K[3][4096] @0, V[3][4096] @12288 (bf16 elems) = 48KB + LP.
// K tile: [kv row 0..63][d-granule swz]; V tile: [d row 0..63][kv-granule swz]
__global__ __launch_bounds__(128) void flash_kernel(const bf16* __restrict__ qk,
                                                    const bf16* __restrict__ Vt,
                                                    bf16* __restrict__ attno) {
    __shared__ __align__(16) bf16 KV[24576];
    __shared__ float LP[128];

    const int t = threadIdx.x;
    const int wid = t >> 6, lane = t & 63;
    const int l31 = lane & 31, hl = lane >> 5;

    // XCD-aware decode: 512 blocks, 64 per XCD, 4 bh per XCD
    const int i0 = blockIdx.x;
    const int xcd = i0 & 7, slot = i0 >> 3;      // slot 0..63
    const int bh = xcd * 4 + (slot >> 4);
    const int qb = slot & 15;                    // 16 q-blocks of 128 rows
    const int b = bh >> 4, h = bh & 15;
    const int rowbase = b * 2048;
    const int q0w = qb * 128 + wid * 64;         // wave covers 64 q (2 groups of 32)

    // Q B-fragments per group (col=q=l31, k=hl*8+e within kstep), pre-scaled
    bf16x8 qfa[4], qfb[4];
    {
        const bf16* qra = qk + (long)(rowbase + q0w + l31) * 2048 + h * 64 + hl * 8;
        const bf16* qrb = qra + 32 * 2048;
        const float qs = 0.18033688f;  // 0.125 * log2(e)
#pragma unroll
        for (int ks = 0; ks < 4; ++ks) {
            bf16x8 a = *(const bf16x8*)(qra + ks * 16);
            bf16x8 d = *(const bf16x8*)(qrb + ks * 16);
#pragma unroll
            for (int e = 0; e < 8; ++e) {
                qfa[ks][e] = (bf16)((float)a[e] * qs);
                qfb[ks][e] = (bf16)((float)d[e] * qs);
            }
        }
    }

    // staging (linear LDS dest + inverse-swizzled global source):
    // issue i covers rows srow0 + i*16; 8 lanes = 128B contiguous per row
    const int srow0 = wid * 8 + ((lane >> 3) & 7);
    const int swcol = ((lane & 7) ^ (srow0 & 7)) * 8;
    const bf16* ksn = qk + (long)(rowbase + srow0) * 2048 + 1024 + h * 64 + swcol;
    const bf16* vsn = Vt + (long)(h * 64 + srow0) * 4096 + b * 2048 + swcol;
    const int kchunk = wid * 512;

    // swizzled read offsets (granule (ks*2+hl) of row l31; rows 32.. at +2048)
    int rdoff[4];
#pragma unroll
    for (int ks = 0; ks < 4; ++ks)
        rdoff[ks] = l31 * 64 + (((ks * 2 + hl) ^ (l31 & 7)) * 8);

    float lpA0 = 0.f, lpB0 = 0.f, lpA1 = 0.f, lpB1 = 0.f;
    f32x16 oacc00 = {}, oacc10 = {}, oacc01 = {}, oacc11 = {};

#define STAGE(BI)                                                        \
    {                                                                    \
        bf16* kd = KV + (BI) * 4096 + kchunk;                            \
        bf16* vd = KV + 12288 + (BI) * 4096 + kchunk;                    \
        gload16(ksn, kd);                                                \
        gload16(ksn + 32768, kd + 1024);                                 \
        gload16(ksn + 65536, kd + 2048);                                 \
        gload16(ksn + 98304, kd + 3072);                                 \
        gload16(vsn, vd);                                                \
        gload16(vsn + 65536, vd + 1024);                                 \
        gload16(vsn + 131072, vd + 2048);                                \
        gload16(vsn + 196608, vd + 3072);                                \
        ksn += 131072;                                                   \
        vsn += 64;                                                       \
    }

    auto compute = [&](int bi) __attribute__((always_inline)) {
        const bf16* Kb = KV + bi * 4096;
        const bf16* Vb = KV + 12288 + bi * 4096;
        // S^T = K Q^T for both q-groups; kf registers shared across groups
        f32x16 s00 = {}, s10 = {}, s01 = {}, s11 = {};
        __builtin_amdgcn_s_setprio(1);
#pragma unroll
        for (int ks = 0; ks < 4; ++ks) {
            bf16x8 kf0 = *(const bf16x8*)(Kb + rdoff[ks]);
            bf16x8 kf1 = *(const bf16x8*)(Kb + 2048 + rdoff[ks]);
            s00 = __builtin_amdgcn_mfma_f32_32x32x16_bf16(kf0, qfa[ks], s00, 0, 0, 0);
            s10 = __builtin_amdgcn_mfma_f32_32x32x16_bf16(kf1, qfa[ks], s10, 0, 0, 0);
            s01 = __builtin_amdgcn_mfma_f32_32x32x16_bf16(kf0, qfb[ks], s01, 0, 0, 0);
            s11 = __builtin_amdgcn_mfma_f32_32x32x16_bf16(kf1, qfb[ks], s11, 0, 0, 0);
        }
        __builtin_amdgcn_s_setprio(0);
        // P = exp2(S); independent denominator chains per group
        float p00[16], p10[16], p01[16], p11[16];
#pragma unroll
        for (int r = 0; r < 16; ++r) p00[r] = fexp2(s00[r]);
#pragma unroll
        for (int r = 0; r < 16; ++r) p10[r] = fexp2(s10[r]);
#pragma unroll
        for (int r = 0; r < 16; ++r) p01[r] = fexp2(s01[r]);
#pragma unroll
        for (int r = 0; r < 16; ++r) p11[r] = fexp2(s11[r]);
#pragma unroll
        for (int r = 0; r < 8; ++r) {
            lpA0 += p00[r] + p10[r];
            lpB0 += p00[r + 8] + p10[r + 8];
            lpA1 += p01[r] + p11[r];
            lpB1 += p01[r + 8] + p11[r + 8];
        }
        // per kstep: vf registers shared across groups; pack via cvt_pk + permlane32_swap
        __builtin_amdgcn_s_setprio(1);
#pragma unroll
        for (int ks = 0; ks < 4; ++ks) {
            bf16x8 vf0 = *(const bf16x8*)(Vb + rdoff[ks]);
            bf16x8 vf1 = *(const bf16x8*)(Vb + 2048 + rdoff[ks]);
            const int s = (ks & 1) * 8;
            {
                const float* pp = (ks < 2) ? p00 : p10;
                unsigned wA, wB, wC, wD;
                asm("v_cvt_pk_bf16_f32 %0, %1, %2" : "=v"(wA) : "v"(pp[s + 0]), "v"(pp[s + 1]));
                asm("v_cvt_pk_bf16_f32 %0, %1, %2" : "=v"(wB) : "v"(pp[s + 4]), "v"(pp[s + 5]));
                asm("v_cvt_pk_bf16_f32 %0, %1, %2" : "=v"(wC) : "v"(pp[s + 2]), "v"(pp[s + 3]));
                asm("v_cvt_pk_bf16_f32 %0, %1, %2" : "=v"(wD) : "v"(pp[s + 6]), "v"(pp[s + 7]));
                asm("v_permlane32_swap_b32 %0, %1" : "+v"(wA), "+v"(wB));
                asm("v_permlane32_swap_b32 %0, %1" : "+v"(wC), "+v"(wD));
                union { unsigned w[4]; bf16x8 v; } pu;
                pu.w[0] = wA; pu.w[1] = wC; pu.w[2] = wB; pu.w[3] = wD;
                oacc00 = __builtin_amdgcn_mfma_f32_32x32x16_bf16(pu.v, vf0, oacc00, 0, 0, 0);
                oacc10 = __builtin_amdgcn_mfma_f32_32x32x16_bf16(pu.v, vf1, oacc10, 0, 0, 0);
            }
            {
                const float* pp = (ks < 2) ? p01 : p11;
                unsigned wA, wB, wC, wD;
                asm("v_cvt_pk_bf16_f32 %0, %1, %2" : "=v"(wA) : "v"(pp[s + 0]), "v"(pp[s + 1]));
                asm("v_cvt_pk_bf16_f32 %0, %1, %2" : "=v"(wB) : "v"(pp[s + 4]), "v"(pp[s + 5]));
                asm("v_cvt_pk_bf16_f32 %0, %1, %2" : "=v"(wC) : "v"(pp[s + 2]), "v"(pp[s + 3]));
                asm("v_cvt_pk_bf16_f32 %0, %1, %2" : "=v"(wD) : "v"(pp[s + 6]), "v"(pp[s + 7]));
                asm("v_permlane32_swap_b32 %0, %1" : "+v"(wA), "+v"(wB));
                asm("v_permlane32_swap_b32 %0, %1" : "+v"(wC), "+v"(wD));
                union { unsigned w[4]; bf16x8 v; } pu;
                pu.w[0] = wA; pu.w[1] = wC; pu.w[2] = wB; pu.w[3] = wD;
                oacc01 = __builtin_amdgcn_mfma_f32_32x32x16_bf16(pu.v, vf0, oacc01, 0, 0, 0);
                oacc11 = __builtin_amdgcn_mfma_f32_32x32x16_bf16(pu.v, vf1, oacc11, 0, 0, 0);
            }
        }
        __builtin_amdgcn_s_setprio(0);
    };

    // prologue: tiles 0,1 in flight (8 DMAs each per wave)
    STAGE(0);
    STAGE(1);

#define FSTEP(CUR, NXT)                                    \
    asm volatile("s_waitcnt vmcnt(8)" ::: "memory");       \
    __builtin_amdgcn_s_barrier();                          \
    STAGE(NXT);                                            \
    compute(CUR);

    for (int t3 = 0; t3 < 10; ++t3) {
        FSTEP(0, 2)
        FSTEP(1, 0)
        FSTEP(2, 1)
    }
    asm volatile("s_waitcnt vmcnt(8)" ::: "memory");
    __builtin_amdgcn_s_barrier();
    compute(0);
    asm volatile("s_waitcnt vmcnt(0)" ::: "memory");
    __builtin_amdgcn_s_barrier();
    compute(1);
#undef FSTEP
#undef STAGE

    // denominators: lanes l / l+32 share q = l31 (per group)
    float lp0 = lpA0 + lpB0;
    float lp1 = lpA1 + lpB1;
    lp0 += __shfl_xor(lp0, 32);
    lp1 += __shfl_xor(lp1, 32);
    if (lane < 32) {
        LP[wid * 64 + l31] = lp0;
        LP[wid * 64 + 32 + l31] = lp1;
    }
    __builtin_amdgcn_s_barrier();  // intra-wave LDS visibility (lanes 32+ read 0-31's writes)

    // store: O[q][d], q = reg-mapped row, d = dh*32 + l31
#pragma unroll
    for (int r = 0; r < 16; ++r) {
        const int qrow = (r & 3) + 8 * (r >> 2) + 4 * hl;
        const float i0v = 1.0f / LP[wid * 64 + qrow];
        const float i1v = 1.0f / LP[wid * 64 + 32 + qrow];
        const long rb0 = (long)(rowbase + q0w + qrow) * 1024 + h * 64 + l31;
        const long rb1 = (long)(rowbase + q0w + 32 + qrow) * 1024 + h * 64 + l31;
        attno[rb0] = (bf16)(oacc00[r] * i0v);
        attno[rb0 + 32] = (bf16)(oacc10[r] * i0v);
        attno[rb1] = (bf16)(oacc01[r] * i1v);
        attno[rb1 + 32] = (bf16)(oacc11[r] * i1v);
    }
}

// ---------------- launch ----------------
extern "C" void kernel_launch(void* const* d_in, const int* in_sizes, int n_in,
                              void* d_out, int out_size, void* d_ws, size_t ws_size,
                              hipStream_t stream) {
    const float* x = (const float*)d_in[0];      // [2,2048,1024]
    const float* wqkv = (const float*)d_in[1];   // [3072,1024]
    const float* wproj = (const float*)d_in[2];  // [1024,1024]
    const float* bproj = (const float*)d_in[3];  // [1024]

    char* ws = (char*)d_ws;
    bf16* xb     = (bf16*)(ws);                  // 8 MB
    bf16* wqkvb  = (bf16*)(ws + 8388608);        // 6 MB
    bf16* wprojb = (bf16*)(ws + 14680064);       // 2 MB
    bf16* qk     = (bf16*)(ws + 16777216);       // 16 MB: [4096][2048] Q|K
    bf16* Vt     = (bf16*)(ws + 33554432);       // 8 MB: [1024][4096] V^T
    bf16* attno  = (bf16*)(ws + 41943040);       // 8 MB
    if (ws_size < 50331648) return;

    cvt3_kernel<<<2048, 256, 0, stream>>>(x, wqkv, wproj, xb, wqkvb, wprojb);

    // qk[4096,2048] = xb[4096,1024] @ wqkvb[0:2048,1024]^T  (Q and K projections)
    gemm_bt<false, 128><<<dim3(16, 32), 256, 0, stream>>>(xb, wqkvb, nullptr, qk,
                                                          4096, 2048, 1024);

    // Vt[1024,4096] = wv[1024,1024] @ xb[4096,1024]^T  (V^T directly)
    gemm_bt<false, 128><<<dim3(32, 8), 256, 0, stream>>>(wqkvb + 2048 * 1024, xb, nullptr, Vt,
                                                         1024, 4096, 1024);

    // attention: 512 blocks (16 q-blocks x 32 bh), 2 waves x 64 q-rows
    flash_kernel<<<512, 128, 0, stream>>>(qk, Vt, attno);

    // out[4096,1024] = attno @ wprojb^T + bias (f32)
    gemm_bt<true, 128><<<dim3(8, 32), 256, 0, stream>>>(attno, wprojb, bproj, d_out,
                                                        4096, 1024, 1024);
}

// Round 12
// 131.533 us; speedup vs baseline: 1.0166x; 1.0166x over previous
//
#include <hip/hip_runtime.h>
#include <stdint.h>

typedef __bf16 bf16;
typedef __bf16 bf16x8 __attribute__((ext_vector_type(8)));
typedef float f32x4 __attribute__((ext_vector_type(4)));
typedef float f32x16 __attribute__((ext_vector_type(16)));

typedef __attribute__((address_space(1))) void gvoid_t;
typedef __attribute__((address_space(3))) void lvoid_t;

__device__ __forceinline__ void gload16(const void* src, void* lds) {
    __builtin_amdgcn_global_load_lds((gvoid_t*)src, (lvoid_t*)lds, 16, 0, 0);
}

// bare v_exp_f32: args bounded (|x| << 126), OCML range guard is dead weight
__device__ __forceinline__ float fexp2(float x) {
    float r;
    asm("v_exp_f32 %0, %1" : "=v"(r) : "v"(x));
    return r;
}

// ---------------- fused f32 -> bf16 convert (x, wqkv, wproj in one launch) ----------------
__global__ __launch_bounds__(256) void cvt3_kernel(const float* __restrict__ x,
                                                   const float* __restrict__ wqkv,
                                                   const float* __restrict__ wproj,
                                                   bf16* __restrict__ xb,
                                                   bf16* __restrict__ wqkvb,
                                                   bf16* __restrict__ wprojb) {
    int idx = blockIdx.x * 256 + threadIdx.x;
    int stride = gridDim.x * 256;
    for (int i = idx; i < 1048576; i += stride) {
        const float* in;
        bf16* out;
        int j;
        if (i < 524288) { in = x; out = xb; j = i; }
        else if (i < 917504) { in = wqkv; out = wqkvb; j = i - 524288; }
        else { in = wproj; out = wprojb; j = i - 917504; }
        const float4* p = (const float4*)in;
        float4 a = p[(long)j * 2], b = p[(long)j * 2 + 1];
        bf16x8 o;
        o[0] = (bf16)a.x; o[1] = (bf16)a.y; o[2] = (bf16)a.z; o[3] = (bf16)a.w;
        o[4] = (bf16)b.x; o[5] = (bf16)b.y; o[6] = (bf16)b.z; o[7] = (bf16)b.w;
        ((bf16x8*)out)[j] = o;
    }
}

// ------- GEMM: C[M,N] = A[M,K] * W[N,K]^T — 3-buffer counted-vmcnt pipeline -------
// NOTE: K-loop is hardcoded for K == 1024 (32 k-steps = 10*3 + 2). All call sites use K=1024.
template <bool F32OUT, int BN>
__global__ __launch_bounds__(256) void gemm_bt(const bf16* __restrict__ A,
                                               const bf16* __restrict__ W,
                                               const float* __restrict__ bias,
                                               void* __restrict__ Cout,
                                               const int M, const int N, const int K) {
    constexpr int NT = BN / 32;            // per-wave n-subtiles
    constexpr int BELEMS = BN * 32;
    __shared__ __align__(16) bf16 Alds[3 * 4096];    // 3 x [128][32]
    __shared__ __align__(16) bf16 Blds[3 * BELEMS];  // 3 x [BN][32]
    const int t = threadIdx.x;
    const int wid = t >> 6, lane = t & 63;
    const int g = lane >> 4, c = lane & 15;
    const int wm = wid >> 1, wn = wid & 1;
    const long bm = (long)blockIdx.y * 128, bn = (long)blockIdx.x * BN;

    f32x4 acc[4][NT] = {};

    const int arow = t >> 2;          // 0..63
    const int acol = (t & 3) * 8;     // elem offset
    const bf16* Asrc = A + (bm + arow) * (long)K + acol;
    const bf16* Bsrc = W + (bn + arow) * (long)K + acol;
    const int dstb = wid * 512;

#define GSTAGE(BI)                                                       \
    {                                                                    \
        bf16* ad = Alds + (BI) * 4096 + dstb;                            \
        bf16* bd = Blds + (BI) * BELEMS + dstb;                          \
        gload16(Asrc, ad);                                               \
        gload16(Asrc + (long)64 * K, ad + 2048);                         \
        gload16(Bsrc, bd);                                               \
        if constexpr (BN == 128) gload16(Bsrc + (long)64 * K, bd + 2048);\
        Asrc += 32;                                                      \
        Bsrc += 32;                                                      \
    }

    auto computeg = [&](int bi) __attribute__((always_inline)) {
        const bf16* Ab = Alds + bi * 4096;
        const bf16* Bb = Blds + bi * BELEMS;
        bf16x8 af[4], bfr[NT];
#pragma unroll
        for (int mt = 0; mt < 4; ++mt)
            af[mt] = *(const bf16x8*)(Ab + (wm * 64 + mt * 16 + c) * 32 + g * 8);
#pragma unroll
        for (int nt = 0; nt < NT; ++nt)
            bfr[nt] = *(const bf16x8*)(Bb + (wn * (BN / 2) + nt * 16 + c) * 32 + g * 8);
#pragma unroll
        for (int mt = 0; mt < 4; ++mt)
#pragma unroll
            for (int nt = 0; nt < NT; ++nt)
                acc[mt][nt] = __builtin_amdgcn_mfma_f32_16x16x32_bf16(af[mt], bfr[nt],
                                                                      acc[mt][nt], 0, 0, 0);
    };

    // steady-state wait: own tile's loads retired (FIFO), next tile's stay in flight
#define GWAITN                                                              \
    if constexpr (BN == 128) { asm volatile("s_waitcnt vmcnt(4)" ::: "memory"); } \
    else { asm volatile("s_waitcnt vmcnt(3)" ::: "memory"); }

#define GSTEP(CUR, NXT)            \
    GWAITN;                        \
    __builtin_amdgcn_s_barrier();  \
    GSTAGE(NXT);                   \
    computeg(CUR);

    GSTAGE(0);
    GSTAGE(1);
    for (int t3 = 0; t3 < 10; ++t3) {
        GSTEP(0, 2)
        GSTEP(1, 0)
        GSTEP(2, 1)
    }
    GWAITN;
    __builtin_amdgcn_s_barrier();
    computeg(0);
    asm volatile("s_waitcnt vmcnt(0)" ::: "memory");
    __builtin_amdgcn_s_barrier();
    computeg(1);
#undef GSTEP
#undef GWAITN
#undef GSTAGE

#pragma unroll
    for (int mt = 0; mt < 4; ++mt) {
#pragma unroll
        for (int nt = 0; nt < NT; ++nt) {
#pragma unroll
            for (int i = 0; i < 4; ++i) {
                const long row = bm + wm * 64 + mt * 16 + g * 4 + i;
                const long col = bn + wn * (BN / 2) + nt * 16 + c;
                if constexpr (F32OUT) {
                    ((float*)Cout)[row * N + col] = acc[mt][nt][i] + bias[col];
                } else {
                    ((bf16*)Cout)[row * N + col] = (bf16)acc[mt][nt][i];
                }
            }
        }
    }
}

// ---- Flash attention, split-KV: 2 waves x 64 q, each block does half the kv range ----
// qk:  [4096 rows][2048] bf16 (Q cols 0-1023, K cols 1024-2047), row = b*2048+s
// Vt:  [1024 hd][4096] bf16 (V^T; col = b*2048 + s)
// Outputs UNNORMALIZED partials (fixed-max softmax => partials are plain sums):
//   P(kvh) bf16 in attno-layout; l(kvh) f32 at [kvh*65536 + bh*2048 + qloc].
// LDS: K[3][4096] @0, V[3][4096] @12288 (bf16) = 48KB + pad.
__global__ __launch_bounds__(128) void flash_kernel(const bf16* __restrict__ qk,
                                                    const bf16* __restrict__ Vt,
                                                    bf16* __restrict__ P0,
                                                    bf16* __restrict__ P1,
                                                    float* __restrict__ lpar) {
    __shared__ __align__(16) bf16 KV[24576];

    const int t = threadIdx.x;
    const int wid = t >> 6, lane = t & 63;
    const int l31 = lane & 31, hl = lane >> 5;

    // decode: 1024 blocks = 8 xcd x (4 bh x 16 qb x 2 kvh)
    const int i0 = blockIdx.x;
    const int xcd = i0 & 7, slot = i0 >> 3;      // slot 0..127
    const int bh = xcd * 4 + (slot >> 5);
    const int rem = slot & 31;
    const int qb = rem >> 1, kvh = rem & 1;
    const int b = bh >> 4, h = bh & 15;
    const int rowbase = b * 2048;
    const int q0w = qb * 128 + wid * 64;         // wave covers 64 q (2 groups of 32)

    // Q B-fragments per group (col=q=l31, k=hl*8+e within kstep), pre-scaled
    bf16x8 qfa[4], qfb[4];
    {
        const bf16* qra = qk + (long)(rowbase + q0w + l31) * 2048 + h * 64 + hl * 8;
        const bf16* qrb = qra + 32 * 2048;
        const float qs = 0.18033688f;  // 0.125 * log2(e)
#pragma unroll
        for (int ks = 0; ks < 4; ++ks) {
            bf16x8 a = *(const bf16x8*)(qra + ks * 16);
            bf16x8 d = *(const bf16x8*)(qrb + ks * 16);
#pragma unroll
            for (int e = 0; e < 8; ++e) {
                qfa[ks][e] = (bf16)((float)a[e] * qs);
                qfb[ks][e] = (bf16)((float)d[e] * qs);
            }
        }
    }

    // staging (linear LDS dest + inverse-swizzled global source); kv origin = kvh*1024
    const int srow0 = wid * 8 + ((lane >> 3) & 7);
    const int swcol = ((lane & 7) ^ (srow0 & 7)) * 8;
    const bf16* ksn = qk + (long)(rowbase + kvh * 1024 + srow0) * 2048 + 1024 + h * 64 + swcol;
    const bf16* vsn = Vt + (long)(h * 64 + srow0) * 4096 + b * 2048 + kvh * 1024 + swcol;
    const int kchunk = wid * 512;

    // swizzled read offsets (granule (ks*2+hl) of row l31; rows 32.. at +2048)
    int rdoff[4];
#pragma unroll
    for (int ks = 0; ks < 4; ++ks)
        rdoff[ks] = l31 * 64 + (((ks * 2 + hl) ^ (l31 & 7)) * 8);

    float lpA0 = 0.f, lpB0 = 0.f, lpA1 = 0.f, lpB1 = 0.f;
    f32x16 oacc00 = {}, oacc10 = {}, oacc01 = {}, oacc11 = {};

#define STAGE(BI)                                                        \
    {                                                                    \
        bf16* kd = KV + (BI) * 4096 + kchunk;                            \
        bf16* vd = KV + 12288 + (BI) * 4096 + kchunk;                    \
        gload16(ksn, kd);                                                \
        gload16(ksn + 32768, kd + 1024);                                 \
        gload16(ksn + 65536, kd + 2048);                                 \
        gload16(ksn + 98304, kd + 3072);                                 \
        gload16(vsn, vd);                                                \
        gload16(vsn + 65536, vd + 1024);                                 \
        gload16(vsn + 131072, vd + 2048);                                \
        gload16(vsn + 196608, vd + 3072);                                \
        ksn += 131072;                                                   \
        vsn += 64;                                                       \
    }

    auto compute = [&](int bi) __attribute__((always_inline)) {
        const bf16* Kb = KV + bi * 4096;
        const bf16* Vb = KV + 12288 + bi * 4096;
        f32x16 s00 = {}, s10 = {}, s01 = {}, s11 = {};
        __builtin_amdgcn_s_setprio(1);
#pragma unroll
        for (int ks = 0; ks < 4; ++ks) {
            bf16x8 kf0 = *(const bf16x8*)(Kb + rdoff[ks]);
            bf16x8 kf1 = *(const bf16x8*)(Kb + 2048 + rdoff[ks]);
            s00 = __builtin_amdgcn_mfma_f32_32x32x16_bf16(kf0, qfa[ks], s00, 0, 0, 0);
            s10 = __builtin_amdgcn_mfma_f32_32x32x16_bf16(kf1, qfa[ks], s10, 0, 0, 0);
            s01 = __builtin_amdgcn_mfma_f32_32x32x16_bf16(kf0, qfb[ks], s01, 0, 0, 0);
            s11 = __builtin_amdgcn_mfma_f32_32x32x16_bf16(kf1, qfb[ks], s11, 0, 0, 0);
        }
        __builtin_amdgcn_s_setprio(0);
        float p00[16], p10[16], p01[16], p11[16];
#pragma unroll
        for (int r = 0; r < 16; ++r) p00[r] = fexp2(s00[r]);
#pragma unroll
        for (int r = 0; r < 16; ++r) p10[r] = fexp2(s10[r]);
#pragma unroll
        for (int r = 0; r < 16; ++r) p01[r] = fexp2(s01[r]);
#pragma unroll
        for (int r = 0; r < 16; ++r) p11[r] = fexp2(s11[r]);
#pragma unroll
        for (int r = 0; r < 8; ++r) {
            lpA0 += p00[r] + p10[r];
            lpB0 += p00[r + 8] + p10[r + 8];
            lpA1 += p01[r] + p11[r];
            lpB1 += p01[r + 8] + p11[r + 8];
        }
        __builtin_amdgcn_s_setprio(1);
#pragma unroll
        for (int ks = 0; ks < 4; ++ks) {
            bf16x8 vf0 = *(const bf16x8*)(Vb + rdoff[ks]);
            bf16x8 vf1 = *(const bf16x8*)(Vb + 2048 + rdoff[ks]);
            const int s = (ks & 1) * 8;
            {
                const float* pp = (ks < 2) ? p00 : p10;
                unsigned wA, wB, wC, wD;
                asm("v_cvt_pk_bf16_f32 %0, %1, %2" : "=v"(wA) : "v"(pp[s + 0]), "v"(pp[s + 1]));
                asm("v_cvt_pk_bf16_f32 %0, %1, %2" : "=v"(wB) : "v"(pp[s + 4]), "v"(pp[s + 5]));
                asm("v_cvt_pk_bf16_f32 %0, %1, %2" : "=v"(wC) : "v"(pp[s + 2]), "v"(pp[s + 3]));
                asm("v_cvt_pk_bf16_f32 %0, %1, %2" : "=v"(wD) : "v"(pp[s + 6]), "v"(pp[s + 7]));
                asm("v_permlane32_swap_b32 %0, %1" : "+v"(wA), "+v"(wB));
                asm("v_permlane32_swap_b32 %0, %1" : "+v"(wC), "+v"(wD));
                union { unsigned w[4]; bf16x8 v; } pu;
                pu.w[0] = wA; pu.w[1] = wC; pu.w[2] = wB; pu.w[3] = wD;
                oacc00 = __builtin_amdgcn_mfma_f32_32x32x16_bf16(pu.v, vf0, oacc00, 0, 0, 0);
                oacc10 = __builtin_amdgcn_mfma_f32_32x32x16_bf16(pu.v, vf1, oacc10, 0, 0, 0);
            }
            {
                const float* pp = (ks < 2) ? p01 : p11;
                unsigned wA, wB, wC, wD;
                asm("v_cvt_pk_bf16_f32 %0, %1, %2" : "=v"(wA) : "v"(pp[s + 0]), "v"(pp[s + 1]));
                asm("v_cvt_pk_bf16_f32 %0, %1, %2" : "=v"(wB) : "v"(pp[s + 4]), "v"(pp[s + 5]));
                asm("v_cvt_pk_bf16_f32 %0, %1, %2" : "=v"(wC) : "v"(pp[s + 2]), "v"(pp[s + 3]));
                asm("v_cvt_pk_bf16_f32 %0, %1, %2" : "=v"(wD) : "v"(pp[s + 6]), "v"(pp[s + 7]));
                asm("v_permlane32_swap_b32 %0, %1" : "+v"(wA), "+v"(wB));
                asm("v_permlane32_swap_b32 %0, %1" : "+v"(wC), "+v"(wD));
                union { unsigned w[4]; bf16x8 v; } pu;
                pu.w[0] = wA; pu.w[1] = wC; pu.w[2] = wB; pu.w[3] = wD;
                oacc01 = __builtin_amdgcn_mfma_f32_32x32x16_bf16(pu.v, vf0, oacc01, 0, 0, 0);
                oacc11 = __builtin_amdgcn_mfma_f32_32x32x16_bf16(pu.v, vf1, oacc11, 0, 0, 0);
            }
        }
        __builtin_amdgcn_s_setprio(0);
    };

    // 16 tiles: prologue 2 + 14 FSTEP (4 triples + 2) + 2 epilogue computes
    STAGE(0);
    STAGE(1);

#define FSTEP(CUR, NXT)                                    \
    asm volatile("s_waitcnt vmcnt(8)" ::: "memory");       \
    __builtin_amdgcn_s_barrier();                          \
    STAGE(NXT);                                            \
    compute(CUR);

    for (int t3 = 0; t3 < 4; ++t3) {
        FSTEP(0, 2)
        FSTEP(1, 0)
        FSTEP(2, 1)
    }
    FSTEP(0, 2)   // compute 12, stage 14
    FSTEP(1, 0)   // compute 13, stage 15
    asm volatile("s_waitcnt vmcnt(8)" ::: "memory");
    __builtin_amdgcn_s_barrier();
    compute(2);   // tile 14
    asm volatile("s_waitcnt vmcnt(0)" ::: "memory");
    __builtin_amdgcn_s_barrier();
    compute(0);   // tile 15
#undef FSTEP
#undef STAGE

    // l partials: lanes l / l+32 share q = l31 (per group); write unnormalized
    float lp0 = lpA0 + lpB0;
    float lp1 = lpA1 + lpB1;
    lp0 += __shfl_xor(lp0, 32);
    lp1 += __shfl_xor(lp1, 32);
    if (lane < 32) {
        const int qloc = qb * 128 + wid * 64 + l31;
        float* lp = lpar + kvh * 65536 + bh * 2048 + qloc;
        lp[0] = lp0;
        lp[32] = lp1;
    }

    // store UNNORMALIZED O partial in attno layout
    bf16* Pd = kvh ? P1 : P0;
#pragma unroll
    for (int r = 0; r < 16; ++r) {
        const int qrow = (r & 3) + 8 * (r >> 2) + 4 * hl;
        const long rb0 = (long)(rowbase + q0w + qrow) * 1024 + h * 64 + l31;
        const long rb1 = (long)(rowbase + q0w + 32 + qrow) * 1024 + h * 64 + l31;
        Pd[rb0] = (bf16)oacc00[r];
        Pd[rb0 + 32] = (bf16)oacc10[r];
        Pd[rb1] = (bf16)oacc01[r];
        Pd[rb1 + 32] = (bf16)oacc11[r];
    }
}

// ---- combine: attno[i] = (P0[i] + P1[i]) / (l0 + l1), in place over P0 ----
__global__ __launch_bounds__(256) void combine_kernel(bf16* __restrict__ P0,
                                                      const bf16* __restrict__ P1,
                                                      const float* __restrict__ lpar) {
    int idx = blockIdx.x * 256 + threadIdx.x;
    int stride = gridDim.x * 256;
    for (int gi = idx; gi < 524288; gi += stride) {
        const int e0 = gi * 8;
        const int row = e0 >> 10, col = e0 & 1023;
        const int li = ((row >> 11) * 16 + (col >> 6)) * 2048 + (row & 2047);
        const float inv = 1.0f / (lpar[li] + lpar[li + 65536]);
        bf16x8 a = ((const bf16x8*)P0)[gi];
        bf16x8 b8 = ((const bf16x8*)P1)[gi];
        bf16x8 o;
#pragma unroll
        for (int e = 0; e < 8; ++e)
            o[e] = (bf16)(((float)a[e] + (float)b8[e]) * inv);
        ((bf16x8*)P0)[gi] = o;
    }
}

// ---------------- launch ----------------
extern "C" void kernel_launch(void* const* d_in, const int* in_sizes, int n_in,
                              void* d_out, int out_size, void* d_ws, size_t ws_size,
                              hipStream_t stream) {
    const float* x = (const float*)d_in[0];      // [2,2048,1024]
    const float* wqkv = (const float*)d_in[1];   // [3072,1024]
    const float* wproj = (const float*)d_in[2];  // [1024,1024]
    const float* bproj = (const float*)d_in[3];  // [1024]

    char* ws = (char*)d_ws;
    bf16* xb     = (bf16*)(ws);                  // 8 MB (dead after Vt GEMM -> P1)
    bf16* P1     = (bf16*)(ws);                  //   flash partial, kv half 1
    bf16* wqkvb  = (bf16*)(ws + 8388608);        // 6 MB (dead after GEMMs -> lpar)
    float* lpar  = (float*)(ws + 8388608);       //   512KB l partials
    bf16* wprojb = (bf16*)(ws + 14680064);       // 2 MB
    bf16* qk     = (bf16*)(ws + 16777216);       // 16 MB: [4096][2048] Q|K
    bf16* Vt     = (bf16*)(ws + 33554432);       // 8 MB: [1024][4096] V^T
    bf16* attno  = (bf16*)(ws + 41943040);       // 8 MB (= flash partial P0, combined in place)
    if (ws_size < 50331648) return;

    cvt3_kernel<<<2048, 256, 0, stream>>>(x, wqkv, wproj, xb, wqkvb, wprojb);

    // qk[4096,2048] = xb[4096,1024] @ wqkvb[0:2048,1024]^T
    gemm_bt<false, 128><<<dim3(16, 32), 256, 0, stream>>>(xb, wqkvb, nullptr, qk,
                                                          4096, 2048, 1024);

    // Vt[1024,4096] = wv[1024,1024] @ xb[4096,1024]^T
    gemm_bt<false, 64><<<dim3(64, 8), 256, 0, stream>>>(wqkvb + 2048 * 1024, xb, nullptr, Vt,
                                                        1024, 4096, 1024);

    // attention partials: 1024 blocks (2 kv-halves), 2 waves x 64 q
    flash_kernel<<<1024, 128, 0, stream>>>(qk, Vt, attno, P1, lpar);

    // combine partials -> attno (in place)
    combine_kernel<<<1024, 256, 0, stream>>>(attno, P1, lpar);

    // out[4096,1024] = attno @ wprojb^T + bias (f32)
    gemm_bt<true, 64><<<dim3(16, 32), 256, 0, stream>>>(attno, wprojb, bproj, d_out,
                                                        4096, 1024, 1024);
}

// Round 17
// 125.981 us; speedup vs baseline: 1.0614x; 1.0441x over previous
//
#include <hip/hip_runtime.h>
#include <stdint.h>

typedef __bf16 bf16;
typedef __bf16 bf16x8 __attribute__((ext_vector_type(8)));
typedef float f32x4 __attribute__((ext_vector_type(4)));
typedef float f32x16 __attribute__((ext_vector_type(16)));

typedef __attribute__((address_space(1))) void gvoid_t;
typedef __attribute__((address_space(3))) void lvoid_t;

__device__ __forceinline__ void gload16(const void* src, void* lds) {
    __builtin_amdgcn_global_load_lds((gvoid_t*)src, (lvoid_t*)lds, 16, 0, 0);
}

// bare v_exp_f32: args bounded (|x| << 126), OCML range guard is dead weight
__device__ __forceinline__ float fexp2(float x) {
    float r;
    asm("v_exp_f32 %0, %1" : "=v"(r) : "v"(x));
    return r;
}

// ---------------- fused f32 -> bf16 convert (x, wqkv, wproj in one launch) ----------------
__global__ __launch_bounds__(256) void cvt3_kernel(const float* __restrict__ x,
                                                   const float* __restrict__ wqkv,
                                                   const float* __restrict__ wproj,
                                                   bf16* __restrict__ xb,
                                                   bf16* __restrict__ wqkvb,
                                                   bf16* __restrict__ wprojb) {
    int idx = blockIdx.x * 256 + threadIdx.x;
    int stride = gridDim.x * 256;
    for (int i = idx; i < 1048576; i += stride) {
        const float* in;
        bf16* out;
        int j;
        if (i < 524288) { in = x; out = xb; j = i; }
        else if (i < 917504) { in = wqkv; out = wqkvb; j = i - 524288; }
        else { in = wproj; out = wprojb; j = i - 917504; }
        const float4* p = (const float4*)in;
        float4 a = p[(long)j * 2], b = p[(long)j * 2 + 1];
        bf16x8 o;
        o[0] = (bf16)a.x; o[1] = (bf16)a.y; o[2] = (bf16)a.z; o[3] = (bf16)a.w;
        o[4] = (bf16)b.x; o[5] = (bf16)b.y; o[6] = (bf16)b.z; o[7] = (bf16)b.w;
        ((bf16x8*)out)[j] = o;
    }
}

// ------- GEMM: C[M,N] = A[M,K] * W[N,K]^T — 3-buffer counted-vmcnt pipeline -------
// Race-hardened: every pipeline wait drains lgkmcnt(0) so this wave's ds_reads of the
// buffer about to be overwritten are COMPLETE before it signals the raw s_barrier
// (raw s_barrier, unlike __syncthreads, does not drain counters itself).
// NOTE: K-loop is hardcoded for K == 1024 (32 k-steps = 10*3 + 2). All call sites use K=1024.
template <bool F32OUT, int BN>
__global__ __launch_bounds__(256) void gemm_bt(const bf16* __restrict__ A,
                                               const bf16* __restrict__ W,
                                               const float* __restrict__ bias,
                                               void* __restrict__ Cout,
                                               const int M, const int N, const int K) {
    constexpr int NT = BN / 32;            // per-wave n-subtiles
    constexpr int BELEMS = BN * 32;
    __shared__ __align__(16) bf16 Alds[3 * 4096];    // 3 x [128][32]
    __shared__ __align__(16) bf16 Blds[3 * BELEMS];  // 3 x [BN][32]
    const int t = threadIdx.x;
    const int wid = t >> 6, lane = t & 63;
    const int g = lane >> 4, c = lane & 15;
    const int wm = wid >> 1, wn = wid & 1;
    const long bm = (long)blockIdx.y * 128, bn = (long)blockIdx.x * BN;

    f32x4 acc[4][NT] = {};

    const int arow = t >> 2;          // 0..63
    const int acol = (t & 3) * 8;     // elem offset
    const bf16* Asrc = A + (bm + arow) * (long)K + acol;
    const bf16* Bsrc = W + (bn + arow) * (long)K + acol;
    const int dstb = wid * 512;

#define GSTAGE(BI)                                                       \
    {                                                                    \
        bf16* ad = Alds + (BI) * 4096 + dstb;                            \
        bf16* bd = Blds + (BI) * BELEMS + dstb;                          \
        gload16(Asrc, ad);                                               \
        gload16(Asrc + (long)64 * K, ad + 2048);                         \
        gload16(Bsrc, bd);                                               \
        if constexpr (BN == 128) gload16(Bsrc + (long)64 * K, bd + 2048);\
        Asrc += 32;                                                      \
        Bsrc += 32;                                                      \
    }

    auto computeg = [&](int bi) __attribute__((always_inline)) {
        const bf16* Ab = Alds + bi * 4096;
        const bf16* Bb = Blds + bi * BELEMS;
        bf16x8 af[4], bfr[NT];
#pragma unroll
        for (int mt = 0; mt < 4; ++mt)
            af[mt] = *(const bf16x8*)(Ab + (wm * 64 + mt * 16 + c) * 32 + g * 8);
#pragma unroll
        for (int nt = 0; nt < NT; ++nt)
            bfr[nt] = *(const bf16x8*)(Bb + (wn * (BN / 2) + nt * 16 + c) * 32 + g * 8);
#pragma unroll
        for (int mt = 0; mt < 4; ++mt)
#pragma unroll
            for (int nt = 0; nt < NT; ++nt)
                acc[mt][nt] = __builtin_amdgcn_mfma_f32_16x16x32_bf16(af[mt], bfr[nt],
                                                                      acc[mt][nt], 0, 0, 0);
    };

    // steady-state wait: own tile's DMAs retired (FIFO) AND own ds_reads complete
#define GWAITN                                                              \
    if constexpr (BN == 128) {                                              \
        asm volatile("s_waitcnt vmcnt(4) lgkmcnt(0)" ::: "memory");         \
    } else {                                                                \
        asm volatile("s_waitcnt vmcnt(3) lgkmcnt(0)" ::: "memory");         \
    }

#define GSTEP(CUR, NXT)            \
    GWAITN;                        \
    __builtin_amdgcn_s_barrier();  \
    GSTAGE(NXT);                   \
    computeg(CUR);

    GSTAGE(0);
    GSTAGE(1);
    for (int t3 = 0; t3 < 10; ++t3) {
        GSTEP(0, 2)
        GSTEP(1, 0)
        GSTEP(2, 1)
    }
    GWAITN;
    __builtin_amdgcn_s_barrier();
    computeg(0);
    asm volatile("s_waitcnt vmcnt(0) lgkmcnt(0)" ::: "memory");
    __builtin_amdgcn_s_barrier();
    computeg(1);
#undef GSTEP
#undef GWAITN
#undef GSTAGE

#pragma unroll
    for (int mt = 0; mt < 4; ++mt) {
#pragma unroll
        for (int nt = 0; nt < NT; ++nt) {
#pragma unroll
            for (int i = 0; i < 4; ++i) {
                const long row = bm + wm * 64 + mt * 16 + g * 4 + i;
                const long col = bn + wn * (BN / 2) + nt * 16 + c;
                if constexpr (F32OUT) {
                    ((float*)Cout)[row * N + col] = acc[mt][nt][i] + bias[col];
                } else {
                    ((bf16*)Cout)[row * N + col] = (bf16)acc[mt][nt][i];
                }
            }
        }
    }
}

// ---- Flash attention: XOR-swizzled LDS (R7 layout), 3-buf counted-vmcnt, setprio ----
// Race-hardened like gemm_bt: pipeline waits drain lgkmcnt(0) before raw s_barrier.
// qk:  [4096 rows][2048] bf16 (Q cols 0-1023, K cols 1024-2047), row = b*2048+s
// Vt:  [1024 hd][4096] bf16 (V^T; col = b*2048 + s)
// LDS: K[3][4096] @0, V[3][4096] @12288 (bf16 elems) = 48KB + LP.
__global__ __launch_bounds__(256) void flash_kernel(const bf16* __restrict__ qk,
                                                    const bf16* __restrict__ Vt,
                                                    bf16* __restrict__ attno) {
    __shared__ __align__(16) bf16 KV[24576];
    __shared__ float LP[128];

    const int t = threadIdx.x;
    const int wid = t >> 6, lane = t & 63;
    const int l31 = lane & 31, hl = lane >> 5;

    // XCD-aware decode: 512 blocks, 64 per XCD, 4 bh per XCD
    const int i0 = blockIdx.x;
    const int xcd = i0 & 7, slot = i0 >> 3;      // slot 0..63
    const int bh = xcd * 4 + (slot >> 4);
    const int qb = slot & 15;                    // 16 q-blocks of 128 rows
    const int b = bh >> 4, h = bh & 15;
    const int rowbase = b * 2048;
    const int q0w = qb * 128 + wid * 32;

    // Q B-fragments (col=q=l31, k=hl*8+e within kstep), pre-scaled by 0.125*log2(e)
    bf16x8 qf[4];
    {
        const bf16* qrow = qk + (long)(rowbase + q0w + l31) * 2048 + h * 64 + hl * 8;
        const float qs = 0.18033688f;
#pragma unroll
        for (int ks = 0; ks < 4; ++ks) {
            bf16x8 a = *(const bf16x8*)(qrow + ks * 16);
#pragma unroll
            for (int e = 0; e < 8; ++e) qf[ks][e] = (bf16)((float)a[e] * qs);
        }
    }

    // staging (linear LDS dest + inverse-swizzled global source): thread covers
    // row srow (and srow+32 on 2nd issue), granule sq; 8 lanes = 128B contiguous/row
    const int srow = t >> 3, sq = t & 7;
    const int swcol = (sq ^ (srow & 7)) * 8;
    const bf16* ksn = qk + (long)(rowbase + srow) * 2048 + 1024 + h * 64 + swcol;
    const bf16* vsn = Vt + (long)(h * 64 + srow) * 4096 + b * 2048 + swcol;
    const int kchunk = wid * 512;

    // swizzled read offsets (granule (ks*2+hl) of row l31, rows 32.. at +2048)
    int rdoff[4];
#pragma unroll
    for (int ks = 0; ks < 4; ++ks)
        rdoff[ks] = l31 * 64 + (((ks * 2 + hl) ^ (l31 & 7)) * 8);

    float lpA = 0.f, lpB = 0.f, lpC = 0.f, lpD = 0.f;
    f32x16 oacc0 = {}, oacc1 = {};

#define STAGE(BI)                                                        \
    {                                                                    \
        bf16* kd = KV + (BI) * 4096 + kchunk;                            \
        bf16* vd = KV + 12288 + (BI) * 4096 + kchunk;                    \
        gload16(ksn, kd);                                                \
        gload16(ksn + 65536, kd + 2048);                                 \
        gload16(vsn, vd);                                                \
        gload16(vsn + 131072, vd + 2048);                                \
        ksn += 131072;                                                   \
        vsn += 64;                                                       \
    }

    auto compute = [&](int bi) __attribute__((always_inline)) {
        const bf16* Kb = KV + bi * 4096;
        const bf16* Vb = KV + 12288 + bi * 4096;
        // S^T = K Q^T : q lane-local
        f32x16 s0 = {}, s1 = {};
        __builtin_amdgcn_s_setprio(1);
#pragma unroll
        for (int ks = 0; ks < 4; ++ks) {
            bf16x8 kf0 = *(const bf16x8*)(Kb + rdoff[ks]);
            bf16x8 kf1 = *(const bf16x8*)(Kb + 2048 + rdoff[ks]);
            s0 = __builtin_amdgcn_mfma_f32_32x32x16_bf16(kf0, qf[ks], s0, 0, 0, 0);
            s1 = __builtin_amdgcn_mfma_f32_32x32x16_bf16(kf1, qf[ks], s1, 0, 0, 0);
        }
        __builtin_amdgcn_s_setprio(0);
        // P = exp2(S); 4 independent denominator chains
        float p0[16], p1[16];
#pragma unroll
        for (int r = 0; r < 16; ++r) p0[r] = fexp2(s0[r]);
#pragma unroll
        for (int r = 0; r < 16; ++r) p1[r] = fexp2(s1[r]);
#pragma unroll
        for (int r = 0; r < 4; ++r) {
            lpA += p0[r * 4 + 0] + p1[r * 4 + 0];
            lpB += p0[r * 4 + 1] + p1[r * 4 + 1];
            lpC += p0[r * 4 + 2] + p1[r * 4 + 2];
            lpD += p0[r * 4 + 3] + p1[r * 4 + 3];
        }
        // per kstep: pack P to bf16 A-frag via cvt_pk + permlane32_swap; PV
        __builtin_amdgcn_s_setprio(1);
#pragma unroll
        for (int ks = 0; ks < 4; ++ks) {
            const float* pp = (ks < 2) ? p0 : p1;
            const int s = (ks & 1) * 8;
            unsigned wA, wB, wC, wD;
            asm("v_cvt_pk_bf16_f32 %0, %1, %2" : "=v"(wA) : "v"(pp[s + 0]), "v"(pp[s + 1]));
            asm("v_cvt_pk_bf16_f32 %0, %1, %2" : "=v"(wB) : "v"(pp[s + 4]), "v"(pp[s + 5]));
            asm("v_cvt_pk_bf16_f32 %0, %1, %2" : "=v"(wC) : "v"(pp[s + 2]), "v"(pp[s + 3]));
            asm("v_cvt_pk_bf16_f32 %0, %1, %2" : "=v"(wD) : "v"(pp[s + 6]), "v"(pp[s + 7]));
            asm("v_permlane32_swap_b32 %0, %1" : "+v"(wA), "+v"(wB));
            asm("v_permlane32_swap_b32 %0, %1" : "+v"(wC), "+v"(wD));
            union { unsigned w[4]; bf16x8 v; } pu;
            pu.w[0] = wA; pu.w[1] = wC; pu.w[2] = wB; pu.w[3] = wD;
            bf16x8 vf0 = *(const bf16x8*)(Vb + rdoff[ks]);
            bf16x8 vf1 = *(const bf16x8*)(Vb + 2048 + rdoff[ks]);
            oacc0 = __builtin_amdgcn_mfma_f32_32x32x16_bf16(pu.v, vf0, oacc0, 0, 0, 0);
            oacc1 = __builtin_amdgcn_mfma_f32_32x32x16_bf16(pu.v, vf1, oacc1, 0, 0, 0);
        }
        __builtin_amdgcn_s_setprio(0);
    };

    // prologue: tiles 0,1 in flight
    STAGE(0);
    STAGE(1);

#define FSTEP(CUR, NXT)                                                  \
    asm volatile("s_waitcnt vmcnt(4) lgkmcnt(0)" ::: "memory");          \
    __builtin_amdgcn_s_barrier();                                        \
    STAGE(NXT);                                                          \
    compute(CUR);

    for (int t3 = 0; t3 < 10; ++t3) {
        FSTEP(0, 2)
        FSTEP(1, 0)
        FSTEP(2, 1)
    }
    asm volatile("s_waitcnt vmcnt(4) lgkmcnt(0)" ::: "memory");
    __builtin_amdgcn_s_barrier();
    compute(0);
    asm volatile("s_waitcnt vmcnt(0) lgkmcnt(0)" ::: "memory");
    __builtin_amdgcn_s_barrier();
    compute(1);
#undef FSTEP
#undef STAGE

    // denominators: lanes l / l+32 share q = l31
    float lpart = (lpA + lpB) + (lpC + lpD);
    lpart += __shfl_xor(lpart, 32);
    if (lane < 32) LP[wid * 32 + l31] = lpart;
    float inv[16];
#pragma unroll
    for (int r = 0; r < 16; ++r) {
        const int qrow = (r & 3) + 8 * (r >> 2) + 4 * hl;
        inv[r] = 1.0f / LP[wid * 32 + qrow];
    }

    // store: O[q][d], q = reg-mapped row, d = dt*32 + l31
#pragma unroll
    for (int r = 0; r < 16; ++r) {
        const int qrow = (r & 3) + 8 * (r >> 2) + 4 * hl;
        const long rbase = (long)(rowbase + q0w + qrow) * 1024 + h * 64 + l31;
        attno[rbase] = (bf16)(oacc0[r] * inv[r]);
        attno[rbase + 32] = (bf16)(oacc1[r] * inv[r]);
    }
}

// ---------------- launch ----------------
extern "C" void kernel_launch(void* const* d_in, const int* in_sizes, int n_in,
                              void* d_out, int out_size, void* d_ws, size_t ws_size,
                              hipStream_t stream) {
    const float* x = (const float*)d_in[0];      // [2,2048,1024]
    const float* wqkv = (const float*)d_in[1];   // [3072,1024]
    const float* wproj = (const float*)d_in[2];  // [1024,1024]
    const float* bproj = (const float*)d_in[3];  // [1024]

    char* ws = (char*)d_ws;
    bf16* xb     = (bf16*)(ws);                  // 8 MB
    bf16* wqkvb  = (bf16*)(ws + 8388608);        // 6 MB
    bf16* wprojb = (bf16*)(ws + 14680064);       // 2 MB
    bf16* qk     = (bf16*)(ws + 16777216);       // 16 MB: [4096][2048] Q|K
    bf16* Vt     = (bf16*)(ws + 33554432);       // 8 MB: [1024][4096] V^T
    bf16* attno  = (bf16*)(ws + 41943040);       // 8 MB
    if (ws_size < 50331648) return;

    cvt3_kernel<<<2048, 256, 0, stream>>>(x, wqkv, wproj, xb, wqkvb, wprojb);

    // qk[4096,2048] = xb[4096,1024] @ wqkvb[0:2048,1024]^T  (Q and K projections)
    gemm_bt<false, 128><<<dim3(16, 32), 256, 0, stream>>>(xb, wqkvb, nullptr, qk,
                                                          4096, 2048, 1024);

    // Vt[1024,4096] = wv[1024,1024] @ xb[4096,1024]^T  (V^T directly) — R10-exact config
    gemm_bt<false, 64><<<dim3(64, 8), 256, 0, stream>>>(wqkvb + 2048 * 1024, xb, nullptr, Vt,
                                                        1024, 4096, 1024);

    // attention: 512 blocks (16 q-blocks x 32 bh), 4 waves x 32 q-rows
    flash_kernel<<<512, 256, 0, stream>>>(qk, Vt, attno);

    // out[4096,1024] = attno @ wprojb^T + bias (f32)
    gemm_bt<true, 64><<<dim3(16, 32), 256, 0, stream>>>(attno, wprojb, bproj, d_out,
                                                        4096, 1024, 1024);
}